// Round 13
// baseline (942.255 us; speedup 1.0000x reference)
//
#include <hip/hip_runtime.h>

#define NN 100000
#define NE 3200000
#define DD 128
#define KC 10
#define NITER 10
#define TILE 128                          // rows per k_iter2 block
#define TTHR 128                          // threads per k_iter2 block
#define NTILE ((NN + TILE - 1) / TILE)    // 782
#define NE4 (NE / 4)

// ---- fused assign+accumulate: LDS-tiled, thread-per-2-rows, K-split-2 ----
// LDS: x 64KB + cs 5KB + wsum 10KB + best 0.5KB ~= 79.5KB -> 2 blocks/CU.
__global__ __launch_bounds__(TTHR) void k_iter2(
    const float* __restrict__ x, const float* __restrict__ csrc,
    float* __restrict__ partial, float* __restrict__ cntpart,
    unsigned char* __restrict__ cl8, int last) {
  __shared__ float4 xt[TILE * 32];   // chunk-XOR swizzled: [row][kc^(row&7)]
  __shared__ float4 cs4[KC * 32];
  __shared__ float wsum[2][KC][DD];
  __shared__ float wcnt[2][KC];
  __shared__ int best[TILE];
  __shared__ float cn[KC];
  const int tid = threadIdx.x;
  const int base = blockIdx.x * TILE;
  const int nvalid = min(TILE, NN - base);
  const float4* __restrict__ xg = (const float4*)x;

  // stage centroids
  for (int i = tid; i < KC * 32; i += TTHR) cs4[i] = ((const float4*)csrc)[i];
  // stage x tile: batched (8 loads in flight, then 8 LDS writes)
  for (int b = 0; b < 4; ++b) {
    float4 v[8];
#pragma unroll
    for (int u = 0; u < 8; ++u) {
      const int i = (b * 8 + u) * TTHR + tid;
      const int row = i >> 5;
      v[u] = (row < nvalid) ? xg[(size_t)(base + row) * 32 + (i & 31)]
                            : float4{0.f, 0.f, 0.f, 0.f};
    }
#pragma unroll
    for (int u = 0; u < 8; ++u) {
      const int i = (b * 8 + u) * TTHR + tid;
      const int row = i >> 5, kc = i & 31;
      xt[row * 32 + (kc ^ (row & 7))] = v[u];
    }
  }
  for (int i = tid; i < 2 * KC * DD; i += TTHR) ((float*)wsum)[i] = 0.f;
  __syncthreads();
  // cnorm (10 threads; overlapped cost is negligible)
  if (tid < KC) {
    float s = 0.f;
    for (int kc = 0; kc < 32; ++kc) {
      const float4 c4 = cs4[tid * 32 + kc];
      s += c4.x * c4.x + c4.y * c4.y + c4.z * c4.z + c4.w * c4.w;
    }
    cn[tid] = s;
  }
  __syncthreads();

  // ---- compute: thread (rp,h) handles rows rp, rp+64, cols [64h,64h+64) ----
  const int rp = tid >> 1, h = tid & 1;
  float d0[KC], d1[KC];
#pragma unroll
  for (int j = 0; j < KC; ++j) {
    d0[j] = 0.f;
    d1[j] = 0.f;
  }
  {
    const float4* __restrict__ xr0 = &xt[rp * 32];
    const float4* __restrict__ xr1 = &xt[(rp + 64) * 32];
    const int xr = rp & 7;  // (rp+64)&7 == rp&7
    for (int c = 0; c < 16; ++c) {
      const int kc = 16 * h + c;
      const float4 a0 = xr0[kc ^ xr];
      const float4 a1 = xr1[kc ^ xr];
#pragma unroll
      for (int j = 0; j < KC; ++j) {
        const float4 cc = cs4[j * 32 + kc];  // broadcast read
        d0[j] += a0.x * cc.x + a0.y * cc.y + a0.z * cc.z + a0.w * cc.w;
        d1[j] += a1.x * cc.x + a1.y * cc.y + a1.z * cc.z + a1.w * cc.w;
      }
    }
  }
  // combine k-halves (lane^1), argmax in h==0 (score = dot - 0.5|c|^2)
#pragma unroll
  for (int j = 0; j < KC; ++j) {
    d0[j] += __shfl_xor(d0[j], 1);
    d1[j] += __shfl_xor(d1[j], 1);
  }
  if (h == 0) {
    int b0 = 0, b1 = 0;
    float m0 = d0[0] - 0.5f * cn[0], m1 = d1[0] - 0.5f * cn[0];
#pragma unroll
    for (int j = 1; j < KC; ++j) {
      const float s0 = d0[j] - 0.5f * cn[j];
      const float s1 = d1[j] - 0.5f * cn[j];
      if (s0 > m0) { m0 = s0; b0 = j; }
      if (s1 > m1) { m1 = s1; b1 = j; }
    }
    best[rp] = (rp < nvalid) ? b0 : 255;
    best[rp + 64] = (rp + 64 < nvalid) ? b1 : 255;
    if (last) {
      if (rp < nvalid) cl8[base + rp] = (unsigned char)b0;
      if (rp + 64 < nvalid) cl8[base + rp + 64] = (unsigned char)b1;
    }
  }
  __syncthreads();

  // ---- accumulate: wave w handles pairs [w*32, w*32+32), R8-style LDS RMW --
  const int w = tid >> 6, lane = tid & 63, half = lane >> 5, hl = lane & 31;
  float cntacc[KC];
#pragma unroll
  for (int j = 0; j < KC; ++j) cntacc[j] = 0.f;
  float* const wrow = &wsum[w][0][hl * 4];
  for (int p = w * 32; p < w * 32 + 32; ++p) {
    const int row = 2 * p + half;
    const float4 v = xt[row * 32 + (hl ^ (row & 7))];
    const int b0 = best[2 * p];       // broadcast
    const int b1 = best[2 * p + 1];   // broadcast
    const int bown = half ? b1 : b0;
#pragma unroll
    for (int j = 0; j < KC; ++j)
      cntacc[j] += (bown == j && hl == 0) ? 1.f : 0.f;
    if (b0 == b1) {  // wave-uniform
      if (b0 != 255) {
        float4 vs;
        vs.x = v.x + __shfl_xor(v.x, 32);
        vs.y = v.y + __shfl_xor(v.y, 32);
        vs.z = v.z + __shfl_xor(v.z, 32);
        vs.w = v.w + __shfl_xor(v.w, 32);
        if (half == 0) {
          float4 t = *(float4*)&wrow[b0 * DD];
          t.x += vs.x; t.y += vs.y; t.z += vs.z; t.w += vs.w;
          *(float4*)&wrow[b0 * DD] = t;
        }
      }
    } else {  // halves target different slots (disjoint addresses)
      if (bown != 255) {
        float4 t = *(float4*)&wrow[bown * DD];
        t.x += v.x; t.y += v.y; t.z += v.z; t.w += v.w;
        *(float4*)&wrow[bown * DD] = t;
      }
    }
  }
  __syncthreads();
  const float* wsf = (const float*)wsum;
  for (int i = tid; i < KC * DD; i += TTHR)
    partial[(size_t)blockIdx.x * (KC * DD) + i] = wsf[i] + wsf[KC * DD + i];
#pragma unroll
  for (int j = 0; j < KC; ++j) cntacc[j] += __shfl_xor(cntacc[j], 32);
  if (lane == 0) {
#pragma unroll
    for (int j = 0; j < KC; ++j) wcnt[w][j] = cntacc[j];
  }
  __syncthreads();
  if (tid < KC)
    cntpart[blockIdx.x * KC + tid] = wcnt[0][tid] + wcnt[1][tid];
}

// ------------- centroid update: block = (j, quarter of columns) -------------
__global__ __launch_bounds__(256) void k_update(
    const float* __restrict__ partial, const float* __restrict__ cntpart,
    float* __restrict__ c) {
  const int j = blockIdx.x >> 2, q = blockIdx.x & 3;  // <<<KC*4, 256>>>
  const int tid = threadIdx.x;
  __shared__ float creds[256];
  __shared__ float red[8][32];
  float cf = 0.f;
  for (int b = tid; b < NTILE; b += 256) cf += cntpart[b * KC + j];
  creds[tid] = cf;
  __syncthreads();
  for (int s = 128; s > 0; s >>= 1) {
    if (tid < s) creds[tid] += creds[tid + s];
    __syncthreads();
  }
  const float denom = fmaxf(creds[0], 1.f);
  const int col = q * 32 + (tid & 31);
  const int r0 = tid >> 5;  // 0..7
  float s0 = 0.f;
  for (int b = r0; b < NTILE; b += 8)
    s0 += partial[(size_t)b * (KC * DD) + j * DD + col];
  red[r0][tid & 31] = s0;
  __syncthreads();
  if (tid < 32) {
    float t = 0.f;
#pragma unroll
    for (int r = 0; r < 8; ++r) t += red[r][tid];
    c[j * DD + q * 32 + tid] = t / denom;
  }
}

// ------------- q/v projection: block = (mat, row i), 128 threads ------------
__global__ __launch_bounds__(DD) void k_qv(const float* __restrict__ c,
                                           const float* __restrict__ WQ,
                                           const float* __restrict__ WV,
                                           float* __restrict__ qv) {
  const int b = blockIdx.x;  // <<<2*KC, DD>>>
  const int mat = b / KC, i = b % KC;
  const float* __restrict__ W = mat ? WV : WQ;
  __shared__ float cr[DD];
  const int k = threadIdx.x;
  cr[k] = c[i * DD + k];
  __syncthreads();
  float a = 0.f;
#pragma unroll 8
  for (int m = 0; m < DD; ++m) a += cr[m] * W[m * DD + k];
  qv[(size_t)mat * KC * DD + i * DD + k] = a;
}

// ------------- 10x10 scores + row softmax -------------
__global__ __launch_bounds__(DD) void k_att(const float* __restrict__ qv,
                                            float* __restrict__ CA) {
  __shared__ float q[KC][DD + 2], v[KC][DD + 2], pr[KC][KC];
  const int tid = threadIdx.x;  // <<<1, DD>>>
  for (int i = 0; i < KC; ++i) {
    q[i][tid] = qv[i * DD + tid];
    v[i][tid] = qv[KC * DD + i * DD + tid];
  }
  __syncthreads();
  if (tid < KC * KC) {
    const int i = tid / KC, l = tid % KC;
    float acc = 0.f;
#pragma unroll 8
    for (int m = 0; m < DD; ++m) acc += q[i][m] * v[l][m];
    pr[i][l] = acc / sqrtf((float)DD);
  }
  __syncthreads();
  if (tid < KC) {
    float mx = pr[tid][0];
    for (int l = 1; l < KC; ++l) mx = fmaxf(mx, pr[tid][l]);
    float e[KC];
    float s = 0.f;
    for (int l = 0; l < KC; ++l) {
      e[l] = expf(pr[tid][l] - mx);
      s += e[l];
    }
    for (int l = 0; l < KC; ++l) CA[tid * KC + l] = e[l] / s;
  }
}

// ------------- edge histogram (4 dispatches for profiler visibility) --------
__global__ __launch_bounds__(256) void k_cnt(const int* __restrict__ e0,
                                             const int* __restrict__ e1,
                                             const unsigned char* __restrict__ cl8,
                                             int* __restrict__ cnt, int base) {
  const int i = base + blockIdx.x * 256 + threadIdx.x;  // int4 index
  if (i >= NE4) return;
  const int4 a = ((const int4*)e0)[i];
  const int4 b = ((const int4*)e1)[i];
  atomicAdd(&cnt[(size_t)a.x * KC + cl8[b.x]], 1);
  atomicAdd(&cnt[(size_t)a.y * KC + cl8[b.y]], 1);
  atomicAdd(&cnt[(size_t)a.z * KC + cl8[b.z]], 1);
  atomicAdd(&cnt[(size_t)a.w * KC + cl8[b.w]], 1);
}

// ------------- per-node denominator (row-max shift) -------------
__global__ __launch_bounds__(256) void k_tab2(
    const unsigned char* __restrict__ cl8, const int* __restrict__ cnt,
    const float* __restrict__ CA, float* __restrict__ den) {
  __shared__ float cas[KC * KC];
  __shared__ float rm[KC];
  if (threadIdx.x < KC * KC) cas[threadIdx.x] = CA[threadIdx.x];
  __syncthreads();
  if (threadIdx.x < KC) {
    float m = cas[threadIdx.x * KC];
    for (int l = 1; l < KC; ++l) m = fmaxf(m, cas[threadIdx.x * KC + l]);
    rm[threadIdx.x] = m;
  }
  __syncthreads();
  const int n = blockIdx.x * 256 + threadIdx.x;
  if (n >= NN) return;
  const int s = cl8[n];
  const float m = rm[s];
  float dsum = 0.f;
#pragma unroll
  for (int j = 0; j < KC; ++j) {
    const int cj = cnt[(size_t)n * KC + j];
    dsum += (float)cj * expf(cas[s * KC + j] - m);
  }
  den[n] = dsum;
}

// ------------- gather: out[e] = exp(ca - rm) / (den + eps) -------------
__global__ __launch_bounds__(256) void k_gather2(
    const int* __restrict__ e0, const int* __restrict__ e1,
    const unsigned char* __restrict__ cl8, const float* __restrict__ CA,
    const float* __restrict__ den, float* __restrict__ out) {
  __shared__ float cas[KC * KC];
  __shared__ float rm[KC];
  if (threadIdx.x < KC * KC) cas[threadIdx.x] = CA[threadIdx.x];
  __syncthreads();
  if (threadIdx.x < KC) {
    float m = cas[threadIdx.x * KC];
    for (int l = 1; l < KC; ++l) m = fmaxf(m, cas[threadIdx.x * KC + l]);
    rm[threadIdx.x] = m;
  }
  __syncthreads();
  const int i = blockIdx.x * 256 + threadIdx.x;  // [0, NE4)
  const int4 a = ((const int4*)e0)[i];
  const int4 b = ((const int4*)e1)[i];
  float4 r;
  {
    const int s = cl8[a.x];
    r.x = expf(cas[s * KC + cl8[b.x]] - rm[s]) / (den[a.x] + 1e-16f);
  }
  {
    const int s = cl8[a.y];
    r.y = expf(cas[s * KC + cl8[b.y]] - rm[s]) / (den[a.y] + 1e-16f);
  }
  {
    const int s = cl8[a.z];
    r.z = expf(cas[s * KC + cl8[b.z]] - rm[s]) / (den[a.z] + 1e-16f);
  }
  {
    const int s = cl8[a.w];
    r.w = expf(cas[s * KC + cl8[b.w]] - rm[s]) / (den[a.w] + 1e-16f);
  }
  ((float4*)out)[i] = r;
}

// ---------------- launch ----------------
extern "C" void kernel_launch(void* const* d_in, const int* in_sizes, int n_in,
                              void* d_out, int out_size, void* d_ws,
                              size_t ws_size, hipStream_t stream) {
  const float* x = (const float*)d_in[0];
  const int* edge = (const int*)d_in[1];
  const float* WQ = (const float*)d_in[2];
  const float* WV = (const float*)d_in[3];
  float* out = (float*)d_out;
  const int* e0 = edge;
  const int* e1 = edge + NE;

  float* ws = (float*)d_ws;
  float* c = ws;                                      // 1280
  float* CA = ws + 1280;                              // 112 (pad)
  float* qv = ws + 1392;                              // 2560
  float* den = qv + 2 * KC * DD;                      // NN
  float* partial = den + NN;                          // NTILE*KC*DD
  float* cntpart = partial + (size_t)NTILE * KC * DD; // NTILE*KC
  int* cnt = (int*)(cntpart + NTILE * KC);            // NN*KC ints
  unsigned char* cl8 = (unsigned char*)(cnt + (size_t)NN * KC);  // NN bytes
  // total ~9.5 MB

  hipMemsetAsync(cnt, 0, (size_t)NN * KC * sizeof(int), stream);

  for (int it = 0; it < NITER; ++it) {
    const float* csrc = (it == 0) ? x : c;
    k_iter2<<<NTILE, TTHR, 0, stream>>>(x, csrc, partial, cntpart, cl8,
                                        it == NITER - 1);
    k_update<<<KC * 4, 256, 0, stream>>>(partial, cntpart, c);
  }
  k_qv<<<2 * KC, DD, 0, stream>>>(c, WQ, WV, qv);
  k_att<<<1, DD, 0, stream>>>(qv, CA);
  const int TOT_BLKS = (NE4 + 255) / 256;  // 3125
  const int QB = (TOT_BLKS + 3) / 4;       // 782
  for (int q = 0; q < 4; ++q) {
    const int nb = (q < 3) ? QB : (TOT_BLKS - 3 * QB);
    k_cnt<<<nb, 256, 0, stream>>>(e0, e1, cl8, cnt, q * QB * 256);
  }
  k_tab2<<<(NN + 255) / 256, 256, 0, stream>>>(cl8, cnt, CA, den);
  k_gather2<<<NE4 / 256, 256, 0, stream>>>(e0, e1, cl8, CA, den, out);
}

// Round 14
// 502.552 us; speedup vs baseline: 1.8749x; 1.8749x over previous
//
#include <hip/hip_runtime.h>

#define NN 100000
#define NE 3200000
#define DD 128
#define KC 10
#define NITER 10
#define NBK 1024            // k_iter blocks; 4 waves each -> 4096 waves
#define NPAIR (NN / 2)
#define NB4 (NPAIR / 4)     // 12500 batches of 4 pairs
#define NE4 (NE / 4)

template <int CTRL, int RM>
__device__ __forceinline__ float dppadd(float v) {
  int t = __builtin_amdgcn_update_dpp(0, __builtin_bit_cast(int, v), CTRL, RM,
                                      0xF, true);
  return v + __builtin_bit_cast(float, t);
}

// After this: lane 31 holds sum of lanes 0..31, lane 63 holds sum of 32..63.
__device__ __forceinline__ float halfsum_tail(float v) {
  v = dppadd<0x111, 0xF>(v);  // row_shr:1
  v = dppadd<0x112, 0xF>(v);  // row_shr:2
  v = dppadd<0x114, 0xF>(v);  // row_shr:4
  v = dppadd<0x118, 0xF>(v);  // row_shr:8
  v = dppadd<0x142, 0xA>(v);  // row_bcast:15 into rows 1,3
  return v;
}
// broadcast lane 31 -> lanes 0..31 and lane 63 -> lanes 32..63
__device__ __forceinline__ int bcast31i(int v) {
  return __builtin_amdgcn_ds_swizzle(v, 0x3E0);
}

// ---- fused assign+accumulate, half-wave per row, 4-pair batched loads ----
// Each wave issues 4x1KB coalesced loads (4KB in flight) before computing.
__global__ __launch_bounds__(256, 2) void k_iter6(
    const float* __restrict__ x, const float* __restrict__ csrc,
    float* __restrict__ partial, float* __restrict__ cntpart,
    unsigned char* __restrict__ cl8, int last) {
  __shared__ float cs[KC][DD];
  __shared__ float wsum[4][KC][DD];
  __shared__ float wcnt[4][KC];
  const int tid = threadIdx.x;
  float* wsf = (float*)wsum;
  for (int i = tid; i < KC * DD; i += 256) ((float*)cs)[i] = csrc[i];
  for (int i = tid; i < 4 * KC * DD; i += 256) wsf[i] = 0.f;
  __syncthreads();
  const int w = tid >> 6, lane = tid & 63, half = lane >> 5, hl = lane & 31;

  float4 cfrag[KC];
  float bias[KC];
#pragma unroll
  for (int j = 0; j < KC; ++j) {
    const float4 c4 = *(const float4*)&cs[j][hl * 4];
    cfrag[j] = c4;
    bias[j] = -0.5f * (c4.x * c4.x + c4.y * c4.y + c4.z * c4.z + c4.w * c4.w);
  }
  float cntacc[KC];
#pragma unroll
  for (int j = 0; j < KC; ++j) cntacc[j] = 0.f;

  float* const wrow = &wsum[w][0][hl * 4];
  const float4* __restrict__ x4 = (const float4*)x;
  const int g = blockIdx.x * 4 + w;  // wave id, 0..4095

  for (int B = g; B < NB4; B += NBK * 4) {
    // issue all 4 loads (rows 8B..8B+7; this half-wave covers 4 of them)
    const size_t rb = (size_t)(8 * B) * 32;
    float4 v[4];
#pragma unroll
    for (int u = 0; u < 4; ++u) v[u] = x4[rb + (size_t)(2 * u + half) * 32 + hl];

#pragma unroll
    for (int u = 0; u < 4; ++u) {
      const int row = 8 * B + 2 * u + half;
      float d[KC];
#pragma unroll
      for (int j = 0; j < KC; ++j)
        d[j] = bias[j] + v[u].x * cfrag[j].x + v[u].y * cfrag[j].y +
               v[u].z * cfrag[j].z + v[u].w * cfrag[j].w;
#pragma unroll
      for (int j = 0; j < KC; ++j) d[j] = halfsum_tail(d[j]);
      int best = 0;  // meaningful in lanes 31/63 only
      float bd = d[0];
#pragma unroll
      for (int j = 1; j < KC; ++j) {
        if (d[j] > bd) { bd = d[j]; best = j; }
      }
      const int bown = bcast31i(best);
      const int bother = __shfl_xor(bown, 32);
#pragma unroll
      for (int j = 0; j < KC; ++j)
        cntacc[j] += (bown == j && hl == 0) ? 1.f : 0.f;
      if (last && hl == 0) cl8[row] = (unsigned char)bown;

      if (bown == bother) {  // wave-uniform: both rows -> same centroid
        float4 vs;
        vs.x = v[u].x + __shfl_xor(v[u].x, 32);
        vs.y = v[u].y + __shfl_xor(v[u].y, 32);
        vs.z = v[u].z + __shfl_xor(v[u].z, 32);
        vs.w = v[u].w + __shfl_xor(v[u].w, 32);
        if (half == 0) {
          float4 t = *(float4*)&wrow[bown * DD];
          t.x += vs.x; t.y += vs.y; t.z += vs.z; t.w += vs.w;
          *(float4*)&wrow[bown * DD] = t;
        }
      } else {  // disjoint LDS addresses
        float4 t = *(float4*)&wrow[bown * DD];
        t.x += v[u].x; t.y += v[u].y; t.z += v[u].z; t.w += v[u].w;
        *(float4*)&wrow[bown * DD] = t;
      }
    }
  }
  // flush
  __syncthreads();
  for (int i = tid; i < KC * DD; i += 256)
    partial[(size_t)blockIdx.x * (KC * DD) + i] =
        wsf[i] + wsf[KC * DD + i] + wsf[2 * KC * DD + i] + wsf[3 * KC * DD + i];
#pragma unroll
  for (int j = 0; j < KC; ++j) cntacc[j] += __shfl_xor(cntacc[j], 32);
  if (half == 0 && hl == 0) {
#pragma unroll
    for (int j = 0; j < KC; ++j) wcnt[w][j] = cntacc[j];
  }
  __syncthreads();
  if (tid < KC)
    cntpart[blockIdx.x * KC + tid] =
        wcnt[0][tid] + wcnt[1][tid] + wcnt[2][tid] + wcnt[3][tid];
}

// ------ centroid update: 160 blocks, block=(j, 8-col group), coalesced ------
__global__ __launch_bounds__(256) void k_update2(
    const float* __restrict__ partial, const float* __restrict__ cntpart,
    float* __restrict__ c) {
  const int j = blockIdx.x >> 4, q = blockIdx.x & 15;  // <<<KC*16, 256>>>
  const int tid = threadIdx.x;
  __shared__ float creds[256];
  __shared__ float red2[32][8];
  float cf = 0.f;
#pragma unroll
  for (int m = 0; m < NBK / 256; ++m) cf += cntpart[(tid + 256 * m) * KC + j];
  creds[tid] = cf;
  __syncthreads();
  for (int s = 128; s > 0; s >>= 1) {
    if (tid < s) creds[tid] += creds[tid + s];
    __syncthreads();
  }
  const float denom = fmaxf(creds[0], 1.f);
  const int cc = tid & 7, r = tid >> 3;  // 8 cols x 32 row-slices
  const int col = j * DD + q * 8 + cc;
  float s0 = 0.f;
#pragma unroll 8
  for (int m = 0; m < NBK / 32; ++m)
    s0 += partial[(size_t)(r + 32 * m) * (KC * DD) + col];
  red2[r][cc] = s0;
  __syncthreads();
  if (tid < 8) {
    float t = 0.f;
#pragma unroll
    for (int rr = 0; rr < 32; ++rr) t += red2[rr][tid];
    c[j * DD + q * 8 + tid] = t / denom;
  }
}

// ------------- q/v projection: block = (mat, row i), 128 threads ------------
__global__ __launch_bounds__(DD) void k_qv(const float* __restrict__ c,
                                           const float* __restrict__ WQ,
                                           const float* __restrict__ WV,
                                           float* __restrict__ qv) {
  const int b = blockIdx.x;  // <<<2*KC, DD>>>
  const int mat = b / KC, i = b % KC;
  const float* __restrict__ W = mat ? WV : WQ;
  __shared__ float cr[DD];
  const int k = threadIdx.x;
  cr[k] = c[i * DD + k];
  __syncthreads();
  float a = 0.f;
#pragma unroll 8
  for (int m = 0; m < DD; ++m) a += cr[m] * W[m * DD + k];
  qv[(size_t)mat * KC * DD + i * DD + k] = a;
}

// ------------- 10x10 scores + row softmax -------------
__global__ __launch_bounds__(DD) void k_att(const float* __restrict__ qv,
                                            float* __restrict__ CA) {
  __shared__ float q[KC][DD + 2], v[KC][DD + 2], pr[KC][KC];
  const int tid = threadIdx.x;  // <<<1, DD>>>
  for (int i = 0; i < KC; ++i) {
    q[i][tid] = qv[i * DD + tid];
    v[i][tid] = qv[KC * DD + i * DD + tid];
  }
  __syncthreads();
  if (tid < KC * KC) {
    const int i = tid / KC, l = tid % KC;
    float acc = 0.f;
#pragma unroll 8
    for (int m = 0; m < DD; ++m) acc += q[i][m] * v[l][m];
    pr[i][l] = acc / sqrtf((float)DD);
  }
  __syncthreads();
  if (tid < KC) {
    float mx = pr[tid][0];
    for (int l = 1; l < KC; ++l) mx = fmaxf(mx, pr[tid][l]);
    float e[KC];
    float s = 0.f;
    for (int l = 0; l < KC; ++l) {
      e[l] = expf(pr[tid][l] - mx);
      s += e[l];
    }
    for (int l = 0; l < KC; ++l) CA[tid * KC + l] = e[l] / s;
  }
}

// ------------- edge histogram (4 dispatches for profiler visibility) --------
__global__ __launch_bounds__(256) void k_cnt(const int* __restrict__ e0,
                                             const int* __restrict__ e1,
                                             const unsigned char* __restrict__ cl8,
                                             int* __restrict__ cnt, int base) {
  const int i = base + blockIdx.x * 256 + threadIdx.x;  // int4 index
  if (i >= NE4) return;
  const int4 a = ((const int4*)e0)[i];
  const int4 b = ((const int4*)e1)[i];
  atomicAdd(&cnt[(size_t)a.x * KC + cl8[b.x]], 1);
  atomicAdd(&cnt[(size_t)a.y * KC + cl8[b.y]], 1);
  atomicAdd(&cnt[(size_t)a.z * KC + cl8[b.z]], 1);
  atomicAdd(&cnt[(size_t)a.w * KC + cl8[b.w]], 1);
}

// ------------- per-node denominator (row-max shift) -------------
__global__ __launch_bounds__(256) void k_tab2(
    const unsigned char* __restrict__ cl8, const int* __restrict__ cnt,
    const float* __restrict__ CA, float* __restrict__ den) {
  __shared__ float cas[KC * KC];
  __shared__ float rm[KC];
  if (threadIdx.x < KC * KC) cas[threadIdx.x] = CA[threadIdx.x];
  __syncthreads();
  if (threadIdx.x < KC) {
    float m = cas[threadIdx.x * KC];
    for (int l = 1; l < KC; ++l) m = fmaxf(m, cas[threadIdx.x * KC + l]);
    rm[threadIdx.x] = m;
  }
  __syncthreads();
  const int n = blockIdx.x * 256 + threadIdx.x;
  if (n >= NN) return;
  const int s = cl8[n];
  const float m = rm[s];
  float dsum = 0.f;
#pragma unroll
  for (int j = 0; j < KC; ++j) {
    const int cj = cnt[(size_t)n * KC + j];
    dsum += (float)cj * expf(cas[s * KC + j] - m);
  }
  den[n] = dsum;
}

// ------------- gather: out[e] = exp(ca - rm) / (den + eps) -------------
__global__ __launch_bounds__(256) void k_gather2(
    const int* __restrict__ e0, const int* __restrict__ e1,
    const unsigned char* __restrict__ cl8, const float* __restrict__ CA,
    const float* __restrict__ den, float* __restrict__ out) {
  __shared__ float cas[KC * KC];
  __shared__ float rm[KC];
  if (threadIdx.x < KC * KC) cas[threadIdx.x] = CA[threadIdx.x];
  __syncthreads();
  if (threadIdx.x < KC) {
    float m = cas[threadIdx.x * KC];
    for (int l = 1; l < KC; ++l) m = fmaxf(m, cas[threadIdx.x * KC + l]);
    rm[threadIdx.x] = m;
  }
  __syncthreads();
  const int i = blockIdx.x * 256 + threadIdx.x;  // [0, NE4)
  const int4 a = ((const int4*)e0)[i];
  const int4 b = ((const int4*)e1)[i];
  float4 r;
  {
    const int s = cl8[a.x];
    r.x = expf(cas[s * KC + cl8[b.x]] - rm[s]) / (den[a.x] + 1e-16f);
  }
  {
    const int s = cl8[a.y];
    r.y = expf(cas[s * KC + cl8[b.y]] - rm[s]) / (den[a.y] + 1e-16f);
  }
  {
    const int s = cl8[a.z];
    r.z = expf(cas[s * KC + cl8[b.z]] - rm[s]) / (den[a.z] + 1e-16f);
  }
  {
    const int s = cl8[a.w];
    r.w = expf(cas[s * KC + cl8[b.w]] - rm[s]) / (den[a.w] + 1e-16f);
  }
  ((float4*)out)[i] = r;
}

// ---------------- launch ----------------
extern "C" void kernel_launch(void* const* d_in, const int* in_sizes, int n_in,
                              void* d_out, int out_size, void* d_ws,
                              size_t ws_size, hipStream_t stream) {
  const float* x = (const float*)d_in[0];
  const int* edge = (const int*)d_in[1];
  const float* WQ = (const float*)d_in[2];
  const float* WV = (const float*)d_in[3];
  float* out = (float*)d_out;
  const int* e0 = edge;
  const int* e1 = edge + NE;

  float* ws = (float*)d_ws;
  float* c = ws;                                     // 1280
  float* CA = ws + 1280;                             // 112 (pad)
  float* qv = ws + 1392;                             // 2560
  float* den = qv + 2 * KC * DD;                     // NN
  float* partial = den + NN;                         // NBK*KC*DD
  float* cntpart = partial + (size_t)NBK * KC * DD;  // NBK*KC
  int* cnt = (int*)(cntpart + NBK * KC);             // NN*KC ints
  unsigned char* cl8 = (unsigned char*)(cnt + (size_t)NN * KC);  // NN bytes
  // total ~9.8 MB

  hipMemsetAsync(cnt, 0, (size_t)NN * KC * sizeof(int), stream);

  for (int it = 0; it < NITER; ++it) {
    const float* csrc = (it == 0) ? x : c;
    k_iter6<<<NBK, 256, 0, stream>>>(x, csrc, partial, cntpart, cl8,
                                     it == NITER - 1);
    k_update2<<<KC * 16, 256, 0, stream>>>(partial, cntpart, c);
  }
  k_qv<<<2 * KC, DD, 0, stream>>>(c, WQ, WV, qv);
  k_att<<<1, DD, 0, stream>>>(qv, CA);
  const int TOT_BLKS = (NE4 + 255) / 256;  // 3125
  const int QB = (TOT_BLKS + 3) / 4;       // 782
  for (int q = 0; q < 4; ++q) {
    const int nb = (q < 3) ? QB : (TOT_BLKS - 3 * QB);
    k_cnt<<<nb, 256, 0, stream>>>(e0, e1, cl8, cnt, q * QB * 256);
  }
  k_tab2<<<(NN + 255) / 256, 256, 0, stream>>>(cl8, cnt, CA, den);
  k_gather2<<<NE4 / 256, 256, 0, stream>>>(e0, e1, cl8, CA, den, out);
}